// Round 9
// baseline (269.227 us; speedup 1.0000x reference)
//
#include <hip/hip_runtime.h>
#include <math.h>

namespace {
constexpr int BATCH = 32;
constexpr int NANCH = 15130;
constexpr int NCLS  = 81;
constexpr int C1    = 80;          // foreground classes
constexpr int MAXO  = 200;
constexpr int APB   = 256;         // anchors per K1 block (= threads)
constexpr int NBLKA = (NANCH + APB - 1) / APB;   // 60
constexpr int CAP   = 1024;        // cand capacity (fallback sort buffer)
constexpr int CAPB  = 768;         // global bucket capacity (mean 434, sigma 20.5)
constexpr int NWORD = 4;           // 256 bits >= 200 for NMS bitmask
constexpr int NBIN  = 2048;        // histogram bins for final top-k select (K3)
constexpr int NBINK2 = 1536;       // histogram bins for K2 select (max used 1281)
constexpr unsigned BINBASE = 0x3D000000u;  // 0.03125f — below any score > 0.05
constexpr int IMGCAP = C1 * MAXO;  // 16000 — worst-case kept per image
}

#define SCORE_TH 0.05f
#define IOU_TH   0.5f

typedef unsigned long long u64;

__device__ __forceinline__ u64 shflx64(u64 v, int mask) {
    int lo = __shfl_xor((int)(unsigned)(v & 0xffffffffull), mask, 64);
    int hi = __shfl_xor((int)(unsigned)(v >> 32), mask, 64);
    return ((u64)(unsigned)hi << 32) | (unsigned)lo;
}

// Descending bitonic sort of P (power of 2) u64 keys in LDS (fallback path).
// Key = (float_bits(score) << 32) | (0xFFFFFFFF - index)
// => order: score desc, then index asc (matches jax.lax.top_k stability).
__device__ __forceinline__ void bitonic_desc(u64* keys, int P,
                                             int tid, int nthr) {
    for (int k = 2; k <= P; k <<= 1) {
        for (int j = k >> 1; j > 0; j >>= 1) {
            for (int i = tid; i < P; i += nthr) {
                int ixj = i ^ j;
                if (ixj > i) {
                    u64 a = keys[i], c = keys[ixj];
                    bool up = ((i & k) == 0);
                    if (up ? (a < c) : (a > c)) { keys[i] = c; keys[ixj] = a; }
                }
            }
            __syncthreads();
        }
    }
}

// Register bitonic sort of 256 keys (one per thread). j<64 phases via
// cross-lane shuffles; j in {64,128} via LDS round-trip. Same network.
__device__ __forceinline__ u64 regsort256(u64 key, u64* lds, int tid) {
    for (int k = 2; k <= 256; k <<= 1) {
        for (int j = k >> 1; j > 0; j >>= 1) {
            u64 pv;
            if (j < 64) {
                pv = shflx64(key, j);
            } else {
                lds[tid] = key;
                __syncthreads();
                pv = lds[tid ^ j];
            }
            bool up = ((tid & k) == 0);
            bool lt = ((tid & j) == 0);
            u64 mx = (key > pv) ? key : pv;
            u64 mn = (key > pv) ? pv : key;
            key = (up == lt) ? mx : mn;
            if (j >= 64) __syncthreads();
        }
    }
    return key;
}

// Kernel 0: zero bucket counters + per-image kept counters.
__global__ __launch_bounds__(256) void ssd_zero_cnt(int* __restrict__ cntg) {
    int i = blockIdx.x * 256 + threadIdx.x;
    if (i < BATCH * C1 + BATCH) cntg[i] = 0;
}

// Kernel 1: one thread per anchor, logits in registers. Threshold decided by
// guard-banded multiply (exact: band falls back to IEEE div); div computed
// only for actual candidates.
__global__ __launch_bounds__(256) void ssd_decode_stats(
    const float* __restrict__ ploc, const float* __restrict__ plabel,
    const float* __restrict__ dboxes,
    float* __restrict__ ltrb, float* __restrict__ rowmax,
    float* __restrict__ rowsum,
    int* __restrict__ cntg, u64* __restrict__ bucket) {
#pragma clang fp contract(off)
    __shared__ int lcnt[C1], lbase[C1], lrank[C1];

    const int tid = threadIdx.x;
    const int b   = blockIdx.x / NBLKA;
    const int n0  = (blockIdx.x % NBLKA) * APB;
    const int n   = n0 + tid;
    const bool act = (n < NANCH);

    if (tid < C1) lcnt[tid] = 0;

    float x[NCLS];
    float s = 1.f;
    u64 w0 = 0, w1 = 0;   // pass-decision bits for classes 1..64, 65..80
    if (act) {
        const float* pl = ploc + (size_t)b * 4 * NANCH + n;
        float px = pl[0], py = pl[NANCH], pw = pl[2 * NANCH],
              ph = pl[3 * NANCH];
        float4 db = reinterpret_cast<const float4*>(dboxes)[n];
        float cx = px * 0.1f * db.z + db.x;
        float cy = py * 0.1f * db.w + db.y;
        float w  = expf(pw * 0.2f) * db.z;
        float h  = expf(ph * 0.2f) * db.w;
        float4 o;
        o.x = cx - 0.5f * w; o.y = cy - 0.5f * h;
        o.z = cx + 0.5f * w; o.w = cy + 0.5f * h;
        reinterpret_cast<float4*>(ltrb)[(size_t)b * NANCH + n] = o;

        const float* pb = plabel + (size_t)b * NCLS * NANCH + n;
#pragma unroll
        for (int c = 0; c < NCLS; ++c) x[c] = pb[(size_t)c * NANCH];

        float m = -INFINITY;
#pragma unroll
        for (int c = 0; c < NCLS; ++c) m = fmaxf(m, x[c]);
#pragma unroll
        for (int c = 0; c < NCLS; ++c) x[c] = expf(x[c] - m);
        s = 0.f;
#pragma unroll
        for (int c = 0; c < NCLS; ++c) s += x[c];   // serial, reference order
        rowmax[(size_t)b * NANCH + n] = m;
        rowsum[(size_t)b * NANCH + n] = s;

        // fl(e/s) > 0.05  <=>  e/s >= 0.05*(1+2^-25)-ish; decide by multiply
        // outside a 2^-21 guard band, IEEE div inside (exact).
        const float sc = s * SCORE_TH;
        const float lo = sc * 0.99999952f;   // (1 - 2^-21)
        const float hi = sc * 1.00000048f;   // (1 + 2^-21)
#pragma unroll
        for (int c = 1; c < NCLS; ++c) {
            float e = x[c];
            bool pass;
            if (e > hi)      pass = true;
            else if (e < lo) pass = false;
            else             pass = ((e / s) > SCORE_TH);
            if (pass) {
                atomicAdd(&lcnt[c - 1], 1);
                if (c <= 64) w0 |= 1ull << (c - 1);
                else         w1 |= 1ull << (c - 65);
            }
        }
    }
    __syncthreads();

    if (tid < C1) {
        int cn = lcnt[tid];
        lbase[tid] = (cn > 0) ? atomicAdd(&cntg[b * C1 + tid], cn) : 0;
        lrank[tid] = 0;
    }
    __syncthreads();

    if (act) {
#pragma unroll
        for (int c = 1; c < NCLS; ++c) {
            bool pass = (c <= 64) ? ((w0 >> (c - 1)) & 1ull)
                                  : ((w1 >> (c - 65)) & 1ull);
            if (pass) {
                int r = atomicAdd(&lrank[c - 1], 1);
                int pos = lbase[c - 1] + r;
                if (pos < CAPB) {
                    float p = x[c] / s;   // exact IEEE div, = reference value
                    bucket[(size_t)(b * C1 + (c - 1)) * CAPB + pos] =
                        ((u64)__float_as_uint(p) << 32)
                        | (u64)(0xFFFFFFFFu - (unsigned)n);
                }
            }
        }
    }
}

// Kernel 2: per (b, class): histogram-select ~top-200, register bitonic sort,
// NMS (div-free IoU predicate with exact guard band), compact kept output.
__global__ __launch_bounds__(256) void ssd_class_nms(
    const float* __restrict__ plabel, const float* __restrict__ rowmax,
    const float* __restrict__ rowsum, const float* __restrict__ ltrb,
    const int* __restrict__ cntg, const u64* __restrict__ bucket,
    float* __restrict__ pcVals, float* __restrict__ pcBoxes,
    int* __restrict__ imgcnt, u64* __restrict__ imglist) {
    __shared__ u64 cand[CAP];                 // 8 KB
    __shared__ unsigned int hist[NBINK2];     // 6 KB (reused as fill scratch)
    __shared__ float4 box4[MAXO];             // 3.2 KB
    __shared__ float areas[MAXO], vs[MAXO];   // 1.6 KB
    __shared__ u64 sup[MAXO][NWORD];          // 6.4 KB
    __shared__ u64 keepw[NWORD], vmaskS[NWORD];
    __shared__ int wtot[4];
    __shared__ int cnt, fillcnt, cutbin, kcnt, kbase;

    const int tid  = threadIdx.x;
    const int lane = tid & 63;
    const int wv   = tid >> 6;
    const int b    = blockIdx.x / C1;
    const int cls  = blockIdx.x % C1 + 1;   // skip background
    const int bc   = b * C1 + (cls - 1);

    for (int i = tid; i < NBINK2; i += 256) hist[i] = 0u;
    if (tid == 0) { cnt = 0; fillcnt = 0; cutbin = 1; kcnt = 0; }
    __syncthreads();

    const float* pl = plabel + ((size_t)b * NCLS + cls) * NANCH;
    const float* rm = rowmax + (size_t)b * NANCH;
    const float* rs = rowsum + (size_t)b * NANCH;
    const u64* bkt = bucket + (size_t)bc * CAPB;

    const int gcount = cntg[bc];
    const bool ovf = (gcount > CAPB);   // uniform; dead in practice
    int gathered;

    if (!ovf) {
        const int count = gcount;
        for (int i = tid; i < count; i += 256) {
            unsigned bits = (unsigned)(bkt[i] >> 32);
            unsigned bin = ((bits - BINBASE) >> 15) + 1u;
            if (bin > NBINK2 - 1) bin = NBINK2 - 1;
            atomicAdd(&hist[bin], 1u);
        }
        __syncthreads();

        const int base = tid * 6;
        int loc = 0;
        for (int k = 0; k < 6; ++k) loc += (int)hist[base + k];
        int sfx = loc;
        for (int off = 1; off < 64; off <<= 1) {
            int t = __shfl_down(sfx, off, 64);
            if (lane + off < 64) sfx += t;
        }
        if (lane == 0) wtot[wv] = sfx;
        __syncthreads();
        int crossSuf = 0;
        for (int w2 = wv + 1; w2 < 4; ++w2) crossSuf += wtot[w2];
        const int nztot = wtot[0] + wtot[1] + wtot[2] + wtot[3];
        {
            int S = (sfx - loc) + crossSuf;
            for (int k = 5; k >= 0; --k) {
                int binv = (int)hist[base + k];
                int Sk = S + binv;
                int bin = base + k;
                if (bin >= 1 && Sk >= MAXO && S < MAXO) cutbin = bin;
                S = Sk;
            }
        }
        __syncthreads();
        const int B = (nztot >= MAXO) ? cutbin : 1;

        for (int i = tid; i < count; i += 256) {
            u64 k = bkt[i];
            unsigned bits = (unsigned)(k >> 32);
            unsigned bin = ((bits - BINBASE) >> 15) + 1u;
            if (bin > NBINK2 - 1) bin = NBINK2 - 1;
            if ((int)bin >= B) {
                int pos = atomicAdd(&cnt, 1);
                if (pos < CAP) cand[pos] = k;
            }
        }
        __syncthreads();
        gathered = min(cnt, CAP);
    } else {
        for (int n = tid; n < NANCH; n += 256) {
            float p = expf(pl[n] - rm[n]) / rs[n];
            if (p > SCORE_TH) {
                int pos = atomicAdd(&cnt, 1);
                if (pos < CAP)
                    cand[pos] = ((u64)__float_as_uint(p) << 32)
                              | (u64)(0xFFFFFFFFu - (unsigned)n);
            }
        }
        __syncthreads();
        gathered = min(cnt, CAP);
    }

    u64 key;
    if (gathered <= 256) {
        key = (tid < gathered) ? cand[tid] : 0ull;
        key = regsort256(key, cand, tid);
    } else {
        int P = 256; while (P < gathered) P <<= 1;
        for (int i = gathered + tid; i < P; i += 256) cand[i] = 0ull;
        __syncthreads();
        bitonic_desc(cand, P, tid, 256);
        key = cand[tid];
    }

    // <200 positives: fill with smallest anchor idx (top_k zero tie-break). Dead.
    if (gathered < MAXO) {
        int* scanb = (int*)hist;
        cand[tid] = key;
        __syncthreads();
        const int need = MAXO - gathered;
        for (int base2 = 0; base2 < NANCH; base2 += 256) {
            if (fillcnt >= need) break;
            int n = base2 + tid;
            int flag = 0;
            if (n < NANCH) {
                float p = expf(pl[n] - rm[n]) / rs[n];
                flag = (p <= SCORE_TH) ? 1 : 0;
            }
            scanb[tid] = flag;
            __syncthreads();
            for (int off = 1; off < 256; off <<= 1) {
                int v  = scanb[tid];
                int vp = (tid >= off) ? scanb[tid - off] : 0;
                __syncthreads();
                scanb[tid] = v + vp;
                __syncthreads();
            }
            int excl = scanb[tid] - flag;
            if (flag && (fillcnt + excl) < need)
                cand[gathered + fillcnt + excl] =
                    (u64)(0xFFFFFFFFu - (unsigned)n);
            __syncthreads();
            if (tid == 0) fillcnt += scanb[255];
            __syncthreads();
        }
        __syncthreads();
        key = cand[tid];
    }

    if (tid < MAXO) {
#pragma clang fp contract(off)
        float sc   = __uint_as_float((unsigned)(key >> 32));
        unsigned n = 0xFFFFFFFFu - (unsigned)(key & 0xFFFFFFFFull);
        float4 bb =
            reinterpret_cast<const float4*>(ltrb)[(size_t)b * NANCH + n];
        box4[tid] = bb;
        areas[tid] = (bb.z - bb.x) * (bb.w - bb.y);
        vs[tid] = sc;
    }
    {
        bool pred = (tid < MAXO) ?
            (__uint_as_float((unsigned)(key >> 32)) > 0.f) : false;
        u64 bal = __ballot(pred);
        if (lane == 0) vmaskS[wv] = bal;
    }
    __syncthreads();

    // Suppression bit-matrix. fl(inter/denom) >= 0.5 decided without div:
    //   2*inter >= denom            -> true   (2*inter exact, denom > 0)
    //   2*inter <= denom*(1-2^-21)  -> false  (quotient < 0.5*(1-2^-22))
    //   else                        -> exact IEEE div (band ~2^-21, ~never)
    if (tid < MAXO) {
#pragma clang fp contract(off)
        const int i = tid;
        float4 bi = box4[i];
        float ai = areas[i];
        u64 m0 = 0, m1 = 0, m2 = 0, m3 = 0;
        for (int j = i + 1; j < MAXO; ++j) {
            float4 bj = box4[j];
            float l = fmaxf(bi.x, bj.x);
            float t = fmaxf(bi.y, bj.y);
            float r = fminf(bi.z, bj.z);
            float d = fminf(bi.w, bj.w);
            float w = fmaxf(r - l, 0.f);
            float h = fmaxf(d - t, 0.f);
            float inter = w * h;
            float denom = ai + areas[j] - inter + 1e-12f;
            float t2 = 2.0f * inter;
            bool supij;
            if (t2 >= denom)                      supij = true;
            else if (t2 <= denom * 0.99999952f)   supij = false;
            else                                  supij = (inter / denom >= IOU_TH);
            if (supij) {
                u64 bit = 1ull << (j & 63);
                switch (j >> 6) {
                    case 0: m0 |= bit; break;
                    case 1: m1 |= bit; break;
                    case 2: m2 |= bit; break;
                    default: m3 |= bit; break;
                }
            }
        }
        sup[i][0] = m0; sup[i][1] = m1; sup[i][2] = m2; sup[i][3] = m3;
    }
    __syncthreads();

    // Greedy propagation with ctz skip (reference recurrence).
    if (tid == 0) {
        u64 v0 = vmaskS[0], v1 = vmaskS[1], v2 = vmaskS[2], v3 = vmaskS[3];
        u64 k0 = ~0ull, k1 = ~0ull, k2 = ~0ull, k3 = ~0ull;
        for (int w = 0; w < 4; ++w) {
            u64 vw = (w == 0) ? v0 : (w == 1) ? v1 : (w == 2) ? v2 : v3;
            u64 kw = (w == 0) ? k0 : (w == 1) ? k1 : (w == 2) ? k2 : k3;
            u64 cur = kw & vw;
            while (cur) {
                int bit = __builtin_ctzll(cur);
                int i = w * 64 + bit;
                k0 &= ~sup[i][0]; k1 &= ~sup[i][1];
                k2 &= ~sup[i][2]; k3 &= ~sup[i][3];
                kw = (w == 0) ? k0 : (w == 1) ? k1 : (w == 2) ? k2 : k3;
                u64 above = (bit == 63) ? 0ull : (~0ull << (bit + 1));
                cur = kw & vw & above;
            }
        }
        keepw[0] = k0; keepw[1] = k1; keepw[2] = k2; keepw[3] = k3;
    }
    __syncthreads();

    bool kp = false;
    if (tid < MAXO) {
        kp = (keepw[tid >> 6] >> (tid & 63)) & 1ull;
        pcVals[(size_t)bc * MAXO + tid] = (kp && vs[tid] > 0.f) ? vs[tid] : 0.f;
        reinterpret_cast<float4*>(pcBoxes + (size_t)bc * MAXO * 4)[tid] =
            box4[tid];
    }

    // Compact kept keys into the per-image list (set-equal to dense nonzeros).
    bool keep_me = (tid < MAXO) && kp && (vs[tid] > 0.f);
    int r = -1;
    if (keep_me) r = atomicAdd(&kcnt, 1);
    __syncthreads();
    if (tid == 0) kbase = (kcnt > 0) ? atomicAdd(&imgcnt[b], kcnt) : 0;
    __syncthreads();
    if (keep_me) {
        unsigned g = (unsigned)((cls - 1) * MAXO + tid);
        imglist[(size_t)b * IMGCAP + kbase + r] =
            ((u64)__float_as_uint(vs[tid]) << 32) | (u64)(0xFFFFFFFFu - g);
    }
}

// Kernel 3: per image, exact top-200. Live path reads the compact kept list
// (~2-4k entries); dense fallback (NZ<200) kept verbatim.
__global__ __launch_bounds__(256) void ssd_final_topk(
    const float* __restrict__ pcVals, const float* __restrict__ pcBoxes,
    const int* __restrict__ imgcnt, const u64* __restrict__ imglist,
    float* __restrict__ out) {
    __shared__ unsigned int hist[NBIN];
    __shared__ u64 cand[CAP];
    __shared__ int wtot[4];
    __shared__ int cnt, cutbin, nztot;

    const int tid  = threadIdx.x;
    const int lane = tid & 63;
    const int wv   = tid >> 6;
    const int b    = blockIdx.x;
    const int TOT  = C1 * MAXO;   // 16000
    const float* pv = pcVals + (size_t)b * TOT;
    const int NZ   = imgcnt[b];

    for (int i = tid; i < NBIN; i += 256) hist[i] = 0u;
    if (tid == 0) { cnt = 0; cutbin = 1; }
    __syncthreads();

    int count;
    if (NZ >= MAXO) {
        // ---- compact path ----
        const u64* lst = imglist + (size_t)b * IMGCAP;
        for (int i = tid; i < NZ; i += 256) {
            unsigned bits = (unsigned)(lst[i] >> 32);
            unsigned bin = ((bits - BINBASE) >> 15) + 1u;
            if (bin > NBIN - 1) bin = NBIN - 1;
            atomicAdd(&hist[bin], 1u);
        }
        __syncthreads();

        const int base = tid * 8;
        int loc = 0;
        for (int k = 0; k < 8; ++k) loc += (int)hist[base + k];
        int sfx = loc;
        for (int off = 1; off < 64; off <<= 1) {
            int t = __shfl_down(sfx, off, 64);
            if (lane + off < 64) sfx += t;
        }
        if (lane == 0) wtot[wv] = sfx;
        __syncthreads();
        int crossSuf = 0;
        for (int w2 = wv + 1; w2 < 4; ++w2) crossSuf += wtot[w2];
        {
            int S = (sfx - loc) + crossSuf;
            for (int k = 7; k >= 0; --k) {
                int binv = (int)hist[base + k];
                int Sk = S + binv;
                int bin = base + k;
                if (bin >= 1 && Sk >= MAXO && S < MAXO) cutbin = bin;
                S = Sk;
            }
        }
        __syncthreads();
        const int B = cutbin;

        for (int i = tid; i < NZ; i += 256) {
            u64 k = lst[i];
            unsigned bits = (unsigned)(k >> 32);
            unsigned bin = ((bits - BINBASE) >> 15) + 1u;
            if (bin > NBIN - 1) bin = NBIN - 1;
            if ((int)bin >= B) {
                int pos = atomicAdd(&cnt, 1);
                if (pos < CAP) cand[pos] = k;
            }
        }
        __syncthreads();
        count = min(cnt, CAP);
    } else {
        // ---- dense fallback (dead in practice) ----
        for (int g = tid; g < TOT; g += 256) {
            float v = pv[g];
            if (v > 0.f) {
                unsigned bits = __float_as_uint(v);
                unsigned bin = ((bits - BINBASE) >> 15) + 1u;
                if (bin > NBIN - 1) bin = NBIN - 1;
                atomicAdd(&hist[bin], 1u);
            }
        }
        __syncthreads();
        const int base = tid * 8;
        int loc = 0;
        for (int k = 0; k < 8; ++k) loc += (int)hist[base + k];
        int sfx = loc;
        for (int off = 1; off < 64; off <<= 1) {
            int t = __shfl_down(sfx, off, 64);
            if (lane + off < 64) sfx += t;
        }
        if (lane == 0) wtot[wv] = sfx;
        __syncthreads();
        int crossSuf = 0;
        for (int w2 = wv + 1; w2 < 4; ++w2) crossSuf += wtot[w2];
        if (tid == 0) nztot = wtot[0] + wtot[1] + wtot[2] + wtot[3];
        {
            int S = (sfx - loc) + crossSuf;
            for (int k = 7; k >= 0; --k) {
                int binv = (int)hist[base + k];
                int Sk = S + binv;
                int bin = base + k;
                if (bin >= 1 && Sk >= MAXO && S < MAXO) cutbin = bin;
                S = Sk;
            }
        }
        __syncthreads();
        int B = (nztot >= MAXO) ? cutbin : 1;

        for (int g = tid; g < TOT; g += 256) {
            float v = pv[g];
            if (v > 0.f) {
                unsigned bits = __float_as_uint(v);
                unsigned bin = ((bits - BINBASE) >> 15) + 1u;
                if (bin > NBIN - 1) bin = NBIN - 1;
                if ((int)bin >= B) {
                    int pos = atomicAdd(&cnt, 1);
                    if (pos < CAP)
                        cand[pos] = ((u64)bits << 32)
                                  | (u64)(0xFFFFFFFFu - (unsigned)g);
                }
            }
        }
        __syncthreads();
        count = min(cnt, CAP);

        if (count < MAXO) {   // zero-fill, smallest flat index first
            if (tid == 0) {
                int c = count;
                for (int g = 0; g < TOT && c < MAXO; ++g) {
                    if (!(pv[g] > 0.f)) {
                        cand[c++] = (u64)(0xFFFFFFFFu - (unsigned)g);
                    }
                }
                cnt = c;
            }
            __syncthreads();
            count = min(cnt, CAP);
        }
    }

    u64 key;
    if (count <= 256) {
        key = (tid < count) ? cand[tid] : 0ull;
        key = regsort256(key, cand, tid);
    } else {
        int P = 256; while (P < count) P <<= 1;
        for (int i = count + tid; i < P; i += 256) cand[i] = 0ull;
        __syncthreads();
        bitonic_desc(cand, P, tid, 256);
        key = cand[tid];
    }

    if (tid < MAXO) {
        float sc      = __uint_as_float((unsigned)(key >> 32));
        unsigned flat = 0xFFFFFFFFu - (unsigned)(key & 0xFFFFFFFFull);
        int cls = (int)(flat / MAXO) + 1;
        const float4 bb =
            reinterpret_cast<const float4*>(pcBoxes)[(size_t)b * TOT + flat];
        reinterpret_cast<float4*>(out)[(size_t)b * MAXO + tid] = bb;
        out[(size_t)BATCH * MAXO * 4 + (size_t)b * MAXO + tid] = (float)cls;
        out[(size_t)BATCH * MAXO * 5 + (size_t)b * MAXO + tid] = sc;
    }
}

extern "C" void kernel_launch(void* const* d_in, const int* in_sizes, int n_in,
                              void* d_out, int out_size, void* d_ws,
                              size_t ws_size, hipStream_t stream) {
    const float* ploc   = (const float*)d_in[0];
    const float* plabel = (const float*)d_in[1];
    const float* dboxes = (const float*)d_in[2];
    float* out = (float*)d_out;

    float* ws      = (float*)d_ws;
    float* ltrb    = ws;                                   // B*N*4
    float* rowmax  = ltrb   + (size_t)BATCH * NANCH * 4;   // B*N
    float* rowsum  = rowmax + (size_t)BATCH * NANCH;       // B*N
    float* pcVals  = rowsum + (size_t)BATCH * NANCH;       // B*80*200
    float* pcBoxes = pcVals + (size_t)BATCH * C1 * MAXO;   // B*80*200*4
    int*   cntg    = (int*)(pcBoxes + (size_t)BATCH * C1 * MAXO * 4);
    int*   imgcnt  = cntg + BATCH * C1;                    // B ints
    char*  after   = (char*)(imgcnt + BATCH);
    u64* bucket = (u64*)(after + ((16 - (((size_t)after) & 15)) & 15));
    u64* imglist = bucket + (size_t)BATCH * C1 * CAPB;     // B * 16000 u64

    ssd_zero_cnt<<<(BATCH * C1 + BATCH + 255) / 256, 256, 0, stream>>>(cntg);
    ssd_decode_stats<<<BATCH * NBLKA, APB, 0, stream>>>(
        ploc, plabel, dboxes, ltrb, rowmax, rowsum, cntg, bucket);
    ssd_class_nms<<<BATCH * C1, 256, 0, stream>>>(
        plabel, rowmax, rowsum, ltrb, cntg, bucket, pcVals, pcBoxes,
        imgcnt, imglist);
    ssd_final_topk<<<BATCH, 256, 0, stream>>>(
        pcVals, pcBoxes, imgcnt, imglist, out);
}

// Round 10
// 238.578 us; speedup vs baseline: 1.1285x; 1.1285x over previous
//
#include <hip/hip_runtime.h>
#include <math.h>

namespace {
constexpr int BATCH = 32;
constexpr int NANCH = 15130;
constexpr int NCLS  = 81;
constexpr int C1    = 80;          // foreground classes
constexpr int MAXO  = 200;
constexpr int APB   = 256;         // anchors per K1 block (= threads)
constexpr int NBLKA = (NANCH + APB - 1) / APB;   // 60
constexpr int CAPK2 = 512;         // K2 cand capacity (live path uses <=256)
constexpr int CAP   = 1024;        // K3 cand capacity
constexpr int CAPB  = 768;         // global bucket capacity (mean 434, sigma 20.5)
constexpr int NWORD = 4;           // 256 bits >= 200 for NMS bitmask
constexpr int NBIN  = 2048;        // histogram bins for K3 select
constexpr int NBINK2 = 768;        // K2 bins (shift 16); max used bin 641
constexpr unsigned BINBASE = 0x3D000000u;  // 0.03125f — below any score > 0.05
constexpr int IMGCAP = C1 * MAXO;  // 16000 — worst-case kept per image
}

#define SCORE_TH 0.05f
#define IOU_TH   0.5f

typedef unsigned long long u64;

__device__ __forceinline__ u64 shflx64(u64 v, int mask) {
    int lo = __shfl_xor((int)(unsigned)(v & 0xffffffffull), mask, 64);
    int hi = __shfl_xor((int)(unsigned)(v >> 32), mask, 64);
    return ((u64)(unsigned)hi << 32) | (unsigned)lo;
}

// Descending bitonic sort of P (power of 2) u64 keys in LDS (fallback path).
// Key = (float_bits(score) << 32) | (0xFFFFFFFF - index)
// => order: score desc, then index asc (matches jax.lax.top_k stability).
__device__ __forceinline__ void bitonic_desc(u64* keys, int P,
                                             int tid, int nthr) {
    for (int k = 2; k <= P; k <<= 1) {
        for (int j = k >> 1; j > 0; j >>= 1) {
            for (int i = tid; i < P; i += nthr) {
                int ixj = i ^ j;
                if (ixj > i) {
                    u64 a = keys[i], c = keys[ixj];
                    bool up = ((i & k) == 0);
                    if (up ? (a < c) : (a > c)) { keys[i] = c; keys[ixj] = a; }
                }
            }
            __syncthreads();
        }
    }
}

// Register bitonic sort of 256 keys (one per thread). j<64 phases via
// cross-lane shuffles; j in {64,128} via LDS round-trip. Same network.
__device__ __forceinline__ u64 regsort256(u64 key, u64* lds, int tid) {
    for (int k = 2; k <= 256; k <<= 1) {
        for (int j = k >> 1; j > 0; j >>= 1) {
            u64 pv;
            if (j < 64) {
                pv = shflx64(key, j);
            } else {
                lds[tid] = key;
                __syncthreads();
                pv = lds[tid ^ j];
            }
            bool up = ((tid & k) == 0);
            bool lt = ((tid & j) == 0);
            u64 mx = (key > pv) ? key : pv;
            u64 mn = (key > pv) ? pv : key;
            key = (up == lt) ? mx : mn;
            if (j >= 64) __syncthreads();
        }
    }
    return key;
}

// Kernel 1: one thread per anchor, 81 logits in registers (launch_bounds
// caps VGPRs at ~170 -> 3 waves/SIMD). Exact reference op order throughout.
__global__ __launch_bounds__(256, 3) void ssd_decode_stats(
    const float* __restrict__ ploc, const float* __restrict__ plabel,
    const float* __restrict__ dboxes,
    float* __restrict__ ltrb, float* __restrict__ rowmax,
    float* __restrict__ rowsum,
    int* __restrict__ cntg, u64* __restrict__ bucket) {
#pragma clang fp contract(off)
    __shared__ int lcnt[C1], lbase[C1], lrank[C1];

    const int tid = threadIdx.x;
    const int b   = blockIdx.x / NBLKA;
    const int n0  = (blockIdx.x % NBLKA) * APB;
    const int n   = n0 + tid;
    const bool act = (n < NANCH);

    if (tid < C1) lcnt[tid] = 0;

    float x[NCLS];
    if (act) {
        const float* pl = ploc + (size_t)b * 4 * NANCH + n;
        float px = pl[0], py = pl[NANCH], pw = pl[2 * NANCH],
              ph = pl[3 * NANCH];
        float4 db = reinterpret_cast<const float4*>(dboxes)[n];
        float cx = px * 0.1f * db.z + db.x;
        float cy = py * 0.1f * db.w + db.y;
        float w  = expf(pw * 0.2f) * db.z;
        float h  = expf(ph * 0.2f) * db.w;
        float4 o;
        o.x = cx - 0.5f * w; o.y = cy - 0.5f * h;
        o.z = cx + 0.5f * w; o.w = cy + 0.5f * h;
        reinterpret_cast<float4*>(ltrb)[(size_t)b * NANCH + n] = o;

        const float* pb = plabel + (size_t)b * NCLS * NANCH + n;
#pragma unroll
        for (int c = 0; c < NCLS; ++c) x[c] = pb[(size_t)c * NANCH];

        float m = -INFINITY;
#pragma unroll
        for (int c = 0; c < NCLS; ++c) m = fmaxf(m, x[c]);
#pragma unroll
        for (int c = 0; c < NCLS; ++c) x[c] = expf(x[c] - m);
        float s = 0.f;
#pragma unroll
        for (int c = 0; c < NCLS; ++c) s += x[c];   // serial, reference order
        rowmax[(size_t)b * NANCH + n] = m;
        rowsum[(size_t)b * NANCH + n] = s;

#pragma unroll
        for (int c = 1; c < NCLS; ++c) {
            x[c] = x[c] / s;   // exact IEEE div = reference value
            if (x[c] > SCORE_TH) atomicAdd(&lcnt[c - 1], 1);
        }
    }
    __syncthreads();

    if (tid < C1) {
        int cn = lcnt[tid];
        lbase[tid] = (cn > 0) ? atomicAdd(&cntg[b * C1 + tid], cn) : 0;
        lrank[tid] = 0;
    }
    __syncthreads();

    if (act) {
#pragma unroll
        for (int c = 1; c < NCLS; ++c) {
            if (x[c] > SCORE_TH) {
                int r = atomicAdd(&lrank[c - 1], 1);
                int pos = lbase[c - 1] + r;
                if (pos < CAPB)
                    bucket[(size_t)(b * C1 + (c - 1)) * CAPB + pos] =
                        ((u64)__float_as_uint(x[c]) << 32)
                        | (u64)(0xFFFFFFFFu - (unsigned)n);
            }
        }
    }
}

// Kernel 2: per (b, class): histogram-select ~top-200, register bitonic sort,
// NMS with chunked mask accumulation + wave-uniform div-free IoU predicate.
__global__ __launch_bounds__(256, 8) void ssd_class_nms(
    const float* __restrict__ plabel, const float* __restrict__ rowmax,
    const float* __restrict__ rowsum, const float* __restrict__ ltrb,
    const int* __restrict__ cntg, const u64* __restrict__ bucket,
    float* __restrict__ pcVals, float* __restrict__ pcBoxes,
    int* __restrict__ imgcnt, u64* __restrict__ imglist) {
    __shared__ u64 cand[CAPK2];               // 4 KB
    __shared__ unsigned int hist[NBINK2];     // 3 KB (reused as fill scratch)
    __shared__ float4 box4[MAXO];             // 3.2 KB
    __shared__ float areas[MAXO], vs[MAXO];   // 1.6 KB
    __shared__ u64 supflat[MAXO * NWORD];     // 6.4 KB
    __shared__ u64 keepw[NWORD], vmaskS[NWORD];
    __shared__ int wtot[4];
    __shared__ int cnt, fillcnt, cutbin, kcnt, kbase;

    const int tid  = threadIdx.x;
    const int lane = tid & 63;
    const int wv   = tid >> 6;
    const int b    = blockIdx.x / C1;
    const int cls  = blockIdx.x % C1 + 1;   // skip background
    const int bc   = b * C1 + (cls - 1);

    for (int i = tid; i < NBINK2; i += 256) hist[i] = 0u;
    if (tid == 0) { cnt = 0; fillcnt = 0; cutbin = 1; kcnt = 0; }
    __syncthreads();

    const float* pl = plabel + ((size_t)b * NCLS + cls) * NANCH;
    const float* rm = rowmax + (size_t)b * NANCH;
    const float* rs = rowsum + (size_t)b * NANCH;
    const u64* bkt = bucket + (size_t)bc * CAPB;

    const int gcount = cntg[bc];
    const bool ovf = (gcount > CAPB);   // uniform; dead in practice
    int gathered;

    if (!ovf) {
        const int count = gcount;
        // Pass 1: histogram (bin = ((bits-BINBASE)>>16)+1, monotone in value).
        for (int i = tid; i < count; i += 256) {
            unsigned bits = (unsigned)(bkt[i] >> 32);
            unsigned bin = ((bits - BINBASE) >> 16) + 1u;
            if (bin > NBINK2 - 1) bin = NBINK2 - 1;
            atomicAdd(&hist[bin], 1u);
        }
        __syncthreads();

        // Per-thread group sum (3 bins), wave suffix-scan, cross-wave combine.
        const int base = tid * 3;
        int loc = (int)hist[base] + (int)hist[base + 1] + (int)hist[base + 2];
        int sfx = loc;
        for (int off = 1; off < 64; off <<= 1) {
            int t = __shfl_down(sfx, off, 64);
            if (lane + off < 64) sfx += t;
        }
        if (lane == 0) wtot[wv] = sfx;
        __syncthreads();
        int crossSuf = 0;
        for (int w2 = wv + 1; w2 < 4; ++w2) crossSuf += wtot[w2];
        const int nztot = wtot[0] + wtot[1] + wtot[2] + wtot[3];
        {
            int S = (sfx - loc) + crossSuf;
            for (int k = 2; k >= 0; --k) {
                int binv = (int)hist[base + k];
                int Sk = S + binv;
                int bin = base + k;
                if (bin >= 1 && Sk >= MAXO && S < MAXO) cutbin = bin;
                S = Sk;
            }
        }
        __syncthreads();
        const int B = (nztot >= MAXO) ? cutbin : 1;

        // Pass 2: gather keys with bin >= B (top-200 subset; ~205 items).
        for (int i = tid; i < count; i += 256) {
            u64 k = bkt[i];
            unsigned bits = (unsigned)(k >> 32);
            unsigned bin = ((bits - BINBASE) >> 16) + 1u;
            if (bin > NBINK2 - 1) bin = NBINK2 - 1;
            if ((int)bin >= B) {
                int pos = atomicAdd(&cnt, 1);
                if (pos < CAPK2) cand[pos] = k;
            }
        }
        __syncthreads();
        gathered = min(cnt, CAPK2);
    } else {
        // Overflow fallback (dead): full rescan, no select.
        for (int n = tid; n < NANCH; n += 256) {
            float p = expf(pl[n] - rm[n]) / rs[n];
            if (p > SCORE_TH) {
                int pos = atomicAdd(&cnt, 1);
                if (pos < CAPK2)
                    cand[pos] = ((u64)__float_as_uint(p) << 32)
                              | (u64)(0xFFFFFFFFu - (unsigned)n);
            }
        }
        __syncthreads();
        gathered = min(cnt, CAPK2);
    }

    u64 key;
    if (gathered <= 256) {
        key = (tid < gathered) ? cand[tid] : 0ull;
        key = regsort256(key, cand, tid);
    } else {
        for (int i = gathered + tid; i < CAPK2; i += 256) cand[i] = 0ull;
        __syncthreads();
        bitonic_desc(cand, CAPK2, tid, 256);
        key = cand[tid];
    }

    // <200 positives: fill with smallest anchor idx (top_k zero tie-break). Dead.
    if (gathered < MAXO) {
        int* scanb = (int*)hist;
        cand[tid] = key;
        __syncthreads();
        const int need = MAXO - gathered;
        for (int base2 = 0; base2 < NANCH; base2 += 256) {
            if (fillcnt >= need) break;
            int n = base2 + tid;
            int flag = 0;
            if (n < NANCH) {
                float p = expf(pl[n] - rm[n]) / rs[n];
                flag = (p <= SCORE_TH) ? 1 : 0;
            }
            scanb[tid] = flag;
            __syncthreads();
            for (int off = 1; off < 256; off <<= 1) {
                int v  = scanb[tid];
                int vp = (tid >= off) ? scanb[tid - off] : 0;
                __syncthreads();
                scanb[tid] = v + vp;
                __syncthreads();
            }
            int excl = scanb[tid] - flag;
            if (flag && (fillcnt + excl) < need)
                cand[gathered + fillcnt + excl] =
                    (u64)(0xFFFFFFFFu - (unsigned)n);
            __syncthreads();
            if (tid == 0) fillcnt += scanb[255];
            __syncthreads();
        }
        __syncthreads();
        key = cand[tid];
    }

    if (tid < MAXO) {
#pragma clang fp contract(off)
        float sc   = __uint_as_float((unsigned)(key >> 32));
        unsigned n = 0xFFFFFFFFu - (unsigned)(key & 0xFFFFFFFFull);
        float4 bb =
            reinterpret_cast<const float4*>(ltrb)[(size_t)b * NANCH + n];
        box4[tid] = bb;
        areas[tid] = (bb.z - bb.x) * (bb.w - bb.y);
        vs[tid] = sc;
    }
    {
        bool pred = (tid < MAXO) ?
            (__uint_as_float((unsigned)(key >> 32)) > 0.f) : false;
        u64 bal = __ballot(pred);
        if (lane == 0) vmaskS[wv] = bal;
    }
    __syncthreads();

    // Suppression bit-matrix, chunked per 64-bit word; single register mask
    // per chunk (no switch). fl(inter/denom) >= 0.5 decided without div:
    //   2*inter >= denom -> true; 2*inter <= denom*(1-2^-21) -> false;
    //   band (width ~2^-21, ~never) -> wave-uniform branch to exact IEEE div.
    if (tid < MAXO) {
#pragma clang fp contract(off)
        const int i = tid;
        float4 bi = box4[i];
        float ai = areas[i];
        for (int w = 0; w < NWORD; ++w) {
            int j0 = max(i + 1, w * 64);
            int j1 = min(MAXO, w * 64 + 64);
            u64 m = 0ull;
            for (int j = j0; j < j1; ++j) {
                float4 bj = box4[j];
                float l = fmaxf(bi.x, bj.x);
                float t = fmaxf(bi.y, bj.y);
                float r = fminf(bi.z, bj.z);
                float d = fminf(bi.w, bj.w);
                float ww = fmaxf(r - l, 0.f);
                float hh = fmaxf(d - t, 0.f);
                float inter = ww * hh;
                float denom = ai + areas[j] - inter + 1e-12f;
                float t2 = inter + inter;   // exact
                bool sup_t = (t2 >= denom);
                bool band = (t2 < denom) && (t2 > denom * 0.99999952f);
                if (__any(band))
                    sup_t = band ? ((inter / denom) >= IOU_TH) : sup_t;
                m |= sup_t ? (1ull << (j - w * 64)) : 0ull;
            }
            supflat[i * NWORD + w] = m;
        }
    }
    __syncthreads();

    // Greedy propagation with ctz skip (reference fori_loop recurrence).
    if (tid == 0) {
        u64 v0 = vmaskS[0], v1 = vmaskS[1], v2 = vmaskS[2], v3 = vmaskS[3];
        u64 k0 = ~0ull, k1 = ~0ull, k2 = ~0ull, k3 = ~0ull;
        for (int w = 0; w < 4; ++w) {
            u64 vw = (w == 0) ? v0 : (w == 1) ? v1 : (w == 2) ? v2 : v3;
            u64 kw = (w == 0) ? k0 : (w == 1) ? k1 : (w == 2) ? k2 : k3;
            u64 cur = kw & vw;
            while (cur) {
                int bit = __builtin_ctzll(cur);
                int i = w * 64 + bit;
                k0 &= ~supflat[i * NWORD + 0];
                k1 &= ~supflat[i * NWORD + 1];
                k2 &= ~supflat[i * NWORD + 2];
                k3 &= ~supflat[i * NWORD + 3];
                kw = (w == 0) ? k0 : (w == 1) ? k1 : (w == 2) ? k2 : k3;
                u64 above = (bit == 63) ? 0ull : (~0ull << (bit + 1));
                cur = kw & vw & above;
            }
        }
        keepw[0] = k0; keepw[1] = k1; keepw[2] = k2; keepw[3] = k3;
    }
    __syncthreads();

    bool kp = false;
    if (tid < MAXO) {
        kp = (keepw[tid >> 6] >> (tid & 63)) & 1ull;
        pcVals[(size_t)bc * MAXO + tid] = (kp && vs[tid] > 0.f) ? vs[tid] : 0.f;
        reinterpret_cast<float4*>(pcBoxes + (size_t)bc * MAXO * 4)[tid] =
            box4[tid];
    }

    // Compact kept keys into the per-image list (set-equal to dense nonzeros).
    bool keep_me = (tid < MAXO) && kp && (vs[tid] > 0.f);
    int r = -1;
    if (keep_me) r = atomicAdd(&kcnt, 1);
    __syncthreads();
    if (tid == 0) kbase = (kcnt > 0) ? atomicAdd(&imgcnt[b], kcnt) : 0;
    __syncthreads();
    if (keep_me) {
        unsigned g = (unsigned)((cls - 1) * MAXO + tid);
        imglist[(size_t)b * IMGCAP + kbase + r] =
            ((u64)__float_as_uint(vs[tid]) << 32) | (u64)(0xFFFFFFFFu - g);
    }
}

// Kernel 3: per image, exact top-200. Live path reads the compact kept list
// (~2-4k entries); dense fallback (NZ<200) kept verbatim.
__global__ __launch_bounds__(256) void ssd_final_topk(
    const float* __restrict__ pcVals, const float* __restrict__ pcBoxes,
    const int* __restrict__ imgcnt, const u64* __restrict__ imglist,
    float* __restrict__ out) {
    __shared__ unsigned int hist[NBIN];
    __shared__ u64 cand[CAP];
    __shared__ int wtot[4];
    __shared__ int cnt, cutbin, nztot;

    const int tid  = threadIdx.x;
    const int lane = tid & 63;
    const int wv   = tid >> 6;
    const int b    = blockIdx.x;
    const int TOT  = C1 * MAXO;   // 16000
    const float* pv = pcVals + (size_t)b * TOT;
    const int NZ   = imgcnt[b];

    for (int i = tid; i < NBIN; i += 256) hist[i] = 0u;
    if (tid == 0) { cnt = 0; cutbin = 1; }
    __syncthreads();

    int count;
    if (NZ >= MAXO) {
        const u64* lst = imglist + (size_t)b * IMGCAP;
        for (int i = tid; i < NZ; i += 256) {
            unsigned bits = (unsigned)(lst[i] >> 32);
            unsigned bin = ((bits - BINBASE) >> 15) + 1u;
            if (bin > NBIN - 1) bin = NBIN - 1;
            atomicAdd(&hist[bin], 1u);
        }
        __syncthreads();

        const int base = tid * 8;
        int loc = 0;
        for (int k = 0; k < 8; ++k) loc += (int)hist[base + k];
        int sfx = loc;
        for (int off = 1; off < 64; off <<= 1) {
            int t = __shfl_down(sfx, off, 64);
            if (lane + off < 64) sfx += t;
        }
        if (lane == 0) wtot[wv] = sfx;
        __syncthreads();
        int crossSuf = 0;
        for (int w2 = wv + 1; w2 < 4; ++w2) crossSuf += wtot[w2];
        {
            int S = (sfx - loc) + crossSuf;
            for (int k = 7; k >= 0; --k) {
                int binv = (int)hist[base + k];
                int Sk = S + binv;
                int bin = base + k;
                if (bin >= 1 && Sk >= MAXO && S < MAXO) cutbin = bin;
                S = Sk;
            }
        }
        __syncthreads();
        const int B = cutbin;

        for (int i = tid; i < NZ; i += 256) {
            u64 k = lst[i];
            unsigned bits = (unsigned)(k >> 32);
            unsigned bin = ((bits - BINBASE) >> 15) + 1u;
            if (bin > NBIN - 1) bin = NBIN - 1;
            if ((int)bin >= B) {
                int pos = atomicAdd(&cnt, 1);
                if (pos < CAP) cand[pos] = k;
            }
        }
        __syncthreads();
        count = min(cnt, CAP);
    } else {
        // Dense fallback (dead in practice).
        for (int g = tid; g < TOT; g += 256) {
            float v = pv[g];
            if (v > 0.f) {
                unsigned bits = __float_as_uint(v);
                unsigned bin = ((bits - BINBASE) >> 15) + 1u;
                if (bin > NBIN - 1) bin = NBIN - 1;
                atomicAdd(&hist[bin], 1u);
            }
        }
        __syncthreads();
        const int base = tid * 8;
        int loc = 0;
        for (int k = 0; k < 8; ++k) loc += (int)hist[base + k];
        int sfx = loc;
        for (int off = 1; off < 64; off <<= 1) {
            int t = __shfl_down(sfx, off, 64);
            if (lane + off < 64) sfx += t;
        }
        if (lane == 0) wtot[wv] = sfx;
        __syncthreads();
        int crossSuf = 0;
        for (int w2 = wv + 1; w2 < 4; ++w2) crossSuf += wtot[w2];
        if (tid == 0) nztot = wtot[0] + wtot[1] + wtot[2] + wtot[3];
        {
            int S = (sfx - loc) + crossSuf;
            for (int k = 7; k >= 0; --k) {
                int binv = (int)hist[base + k];
                int Sk = S + binv;
                int bin = base + k;
                if (bin >= 1 && Sk >= MAXO && S < MAXO) cutbin = bin;
                S = Sk;
            }
        }
        __syncthreads();
        int B = (nztot >= MAXO) ? cutbin : 1;

        for (int g = tid; g < TOT; g += 256) {
            float v = pv[g];
            if (v > 0.f) {
                unsigned bits = __float_as_uint(v);
                unsigned bin = ((bits - BINBASE) >> 15) + 1u;
                if (bin > NBIN - 1) bin = NBIN - 1;
                if ((int)bin >= B) {
                    int pos = atomicAdd(&cnt, 1);
                    if (pos < CAP)
                        cand[pos] = ((u64)bits << 32)
                                  | (u64)(0xFFFFFFFFu - (unsigned)g);
                }
            }
        }
        __syncthreads();
        count = min(cnt, CAP);

        if (count < MAXO) {   // zero-fill, smallest flat index first
            if (tid == 0) {
                int c = count;
                for (int g = 0; g < TOT && c < MAXO; ++g) {
                    if (!(pv[g] > 0.f)) {
                        cand[c++] = (u64)(0xFFFFFFFFu - (unsigned)g);
                    }
                }
                cnt = c;
            }
            __syncthreads();
            count = min(cnt, CAP);
        }
    }

    u64 key;
    if (count <= 256) {
        key = (tid < count) ? cand[tid] : 0ull;
        key = regsort256(key, cand, tid);
    } else {
        int P = 256; while (P < count) P <<= 1;
        for (int i = count + tid; i < P; i += 256) cand[i] = 0ull;
        __syncthreads();
        bitonic_desc(cand, P, tid, 256);
        key = cand[tid];
    }

    if (tid < MAXO) {
        float sc      = __uint_as_float((unsigned)(key >> 32));
        unsigned flat = 0xFFFFFFFFu - (unsigned)(key & 0xFFFFFFFFull);
        int cls = (int)(flat / MAXO) + 1;
        const float4 bb =
            reinterpret_cast<const float4*>(pcBoxes)[(size_t)b * TOT + flat];
        reinterpret_cast<float4*>(out)[(size_t)b * MAXO + tid] = bb;
        out[(size_t)BATCH * MAXO * 4 + (size_t)b * MAXO + tid] = (float)cls;
        out[(size_t)BATCH * MAXO * 5 + (size_t)b * MAXO + tid] = sc;
    }
}

extern "C" void kernel_launch(void* const* d_in, const int* in_sizes, int n_in,
                              void* d_out, int out_size, void* d_ws,
                              size_t ws_size, hipStream_t stream) {
    const float* ploc   = (const float*)d_in[0];
    const float* plabel = (const float*)d_in[1];
    const float* dboxes = (const float*)d_in[2];
    float* out = (float*)d_out;

    float* ws      = (float*)d_ws;
    float* ltrb    = ws;                                   // B*N*4
    float* rowmax  = ltrb   + (size_t)BATCH * NANCH * 4;   // B*N
    float* rowsum  = rowmax + (size_t)BATCH * NANCH;       // B*N
    float* pcVals  = rowsum + (size_t)BATCH * NANCH;       // B*80*200
    float* pcBoxes = pcVals + (size_t)BATCH * C1 * MAXO;   // B*80*200*4
    int*   cntg    = (int*)(pcBoxes + (size_t)BATCH * C1 * MAXO * 4);
    int*   imgcnt  = cntg + BATCH * C1;                    // B ints
    char*  after   = (char*)(imgcnt + BATCH);
    u64* bucket = (u64*)(after + ((16 - (((size_t)after) & 15)) & 15));
    u64* imglist = bucket + (size_t)BATCH * C1 * CAPB;     // B * 16000 u64

    hipMemsetAsync(cntg, 0, (size_t)(BATCH * C1 + BATCH) * sizeof(int), stream);
    ssd_decode_stats<<<BATCH * NBLKA, APB, 0, stream>>>(
        ploc, plabel, dboxes, ltrb, rowmax, rowsum, cntg, bucket);
    ssd_class_nms<<<BATCH * C1, 256, 0, stream>>>(
        plabel, rowmax, rowsum, ltrb, cntg, bucket, pcVals, pcBoxes,
        imgcnt, imglist);
    ssd_final_topk<<<BATCH, 256, 0, stream>>>(
        pcVals, pcBoxes, imgcnt, imglist, out);
}